// Round 13
// baseline (3393.479 us; speedup 1.0000x reference)
//
#include <hip/hip_runtime.h>

// TemporalGAT: LSTM(T=64,H=128) -> ReLU -> GCNConv -> ReLU -> GATConv(3x64) -> mean
// Round 13: software-pipeline the barrier-free LSTM's A-fragment stream.
// r12 evidence: VGPR_Count=64 -> compiler kept ONE ds_read in flight in the
// load->MFMA distance-1 inner loop (16 x ~120cyc serial latency per cg-group =
// measured 22.5k cyc/step). Fix: double-buffered Af[2][16] (128 VGPRs) --
// issue all 16 prefetch reads for cg+1, MFMA on the resident set (lgkmcnt
// already drained), update while prefetch flies. LDS-BW floor ~130-200us.

#define N_NODES 20000
#define T_STEPS 64
#define N_EDGES 640000
#define HDIM    128
#define JOUT    192   // HEADS*OUT = 3*64
#define NEG_SLOPE 0.2f
#define NBW     16    // nodes per wave
#define WAVES   5
#define NBB     (NBW * WAVES)   // 80 nodes per block
#define LDS_W     131072                  // packed Whh fp16
#define LDS_BW    4096                    // (bias, wih) float2[512]
#define LDS_SCR   (WAVES * 4096)          // per-wave h scratch
#define LDS_TOTAL (LDS_W + LDS_BW + LDS_SCR)   // 155648

typedef _Float16 half8 __attribute__((ext_vector_type(8)));
typedef _Float16 half4v __attribute__((ext_vector_type(4)));
typedef float floatx4 __attribute__((ext_vector_type(4)));

__device__ __forceinline__ float lrelu(float x) { return x > 0.f ? x : NEG_SLOPE * x; }

// ---------------------------------------------------------------------------
// Pre-pack Whh (fp32 [512][128]) into fp16 MFMA A-fragment order:
// frag i = (tile = nt*4+kt, lane): 8 halves = Whh[nt*16 + (lane&15)][kt*32 + (lane>>4)*8 + j]
__global__ void pack_whh_kernel(const float* __restrict__ Whh,
                                _Float16* __restrict__ Wpack)
{
  int i = blockIdx.x * 256 + threadIdx.x;   // 0..8191
  int tile = i >> 6, lane = i & 63;
  int nt = tile >> 2, kt = tile & 3;
  int row = nt * 16 + (lane & 15);
  int c0  = kt * 32 + (lane >> 4) * 8;
  half8 v;
  #pragma unroll
  for (int j = 0; j < 8; ++j)
    v[j] = (_Float16)Whh[row * 128 + c0 + j];
  *(half8*)&Wpack[(size_t)i * 8] = v;
}

// ---------------------------------------------------------------------------
// Barrier-free LSTM. Block = 320 threads (5 waves), 80 nodes. Wave w owns nodes
// n0+w*16..+15 and computes all 512 gate rows per step:
//   G^T[gate][node] = Whh(A, LDS frags) x h(B, regs)  via 128 MFMAs/step.
// A-frags double-buffered in registers (prefetch cg+1 during cg's MFMA/update).
// h round-trips through wave-private scratch (lgkmcnt order, no block barrier).
__global__ __launch_bounds__(320, 1) void lstm_stream_kernel(
    const float* __restrict__ xfeat, const _Float16* __restrict__ Wpack,
    const float* __restrict__ Wih, const float* __restrict__ bih,
    const float* __restrict__ bhh, float* __restrict__ x1)
{
  extern __shared__ char dynlds[];
  _Float16* Wl  = (_Float16*)dynlds;                    // [128 tiles][64 lanes][8]
  float2*   bw  = (float2*)(dynlds + LDS_W);            // [512] (bias, wih)
  _Float16* scr = (_Float16*)(dynlds + LDS_W + LDS_BW); // [5][2048]

  const int tid  = threadIdx.x;   // 0..319
  const int w    = tid >> 6;      // wave 0..4
  const int ln   = tid & 63;
  const int nl   = ln & 15;       // node within wave
  const int quad = ln >> 4;
  const int n0   = blockIdx.x * NBB + w * NBW;

  // stage packed Whh -> LDS (coalesced float4)
  {
    const float4* src = (const float4*)Wpack;
    float4* dst = (float4*)Wl;
    for (int i = tid; i < LDS_W / 16; i += 320) dst[i] = src[i];
  }
  for (int i = tid; i < 512; i += 320)
    bw[i] = make_float2(bih[i] + bhh[i], Wih[i]);
  {
    float4* z = (float4*)scr;
    for (int i = tid; i < LDS_SCR / 16; i += 320)
      z[i] = make_float4(0.f, 0.f, 0.f, 0.f);
  }
  __syncthreads();   // the ONLY block barrier

  _Float16* myscr = scr + w * 2048;
  const float* xrow = xfeat + (size_t)(n0 + nl) * T_STEPS;

  float cst[8][4];
  #pragma unroll
  for (int cg = 0; cg < 8; ++cg)
    #pragma unroll
    for (int r = 0; r < 4; ++r) cst[cg][r] = 0.f;

  const int wq_hi = quad >> 1;
  const int j0    = (quad & 1) * 4;

  half8 Af[2][16];   // double-buffered A fragments (128 VGPRs)

  #pragma unroll 1
  for (int t = 0; t < T_STEPS; ++t) {
    // h of previous step as B-fragments (wave-private scratch, seq addresses)
    half8 Bf[4];
    #pragma unroll
    for (int kt = 0; kt < 4; ++kt)
      Bf[kt] = *(const half8*)&myscr[kt * 512 + ln * 8];
    const float xv = xrow[t];

    // prime cg=0 fragments
    #pragma unroll
    for (int kt = 0; kt < 4; ++kt)
      #pragma unroll
      for (int g = 0; g < 4; ++g)
        Af[0][kt * 4 + g] =
            *(const half8*)&Wl[(size_t)(((g * 8 + 0) * 4 + kt) * 64 + ln) * 8];

    #pragma unroll 1
    for (int cg = 0; cg < 8; ++cg) {
      const int cur = cg & 1, nxt = cur ^ 1;
      // issue prefetch for cg+1 (16 reads in flight during MFMA + update)
      if (cg < 7) {
        #pragma unroll
        for (int kt = 0; kt < 4; ++kt)
          #pragma unroll
          for (int g = 0; g < 4; ++g)
            Af[nxt][kt * 4 + g] =
                *(const half8*)&Wl[(size_t)(((g * 8 + cg + 1) * 4 + kt) * 64 + ln) * 8];
      }
      // init: bias + x * Wih (broadcast LDS reads)
      floatx4 acc[4];
      #pragma unroll
      for (int g = 0; g < 4; ++g) {
        const int base = g * 128 + cg * 16 + quad * 4;
        const float4 p0 = *(const float4*)&bw[base];
        const float4 p1 = *(const float4*)&bw[base + 2];
        acc[g][0] = p0.x + xv * p0.y;
        acc[g][1] = p0.z + xv * p0.w;
        acc[g][2] = p1.x + xv * p1.y;
        acc[g][3] = p1.z + xv * p1.w;
      }
      // G^T += Whh * h on the resident fragment set (no lgkmcnt wait)
      #pragma unroll
      for (int kt = 0; kt < 4; ++kt)
        #pragma unroll
        for (int g = 0; g < 4; ++g)
          acc[g] = __builtin_amdgcn_mfma_f32_16x16x32_f16(
              Af[cur][kt * 4 + g], Bf[kt], acc[g], 0, 0, 0);
      // fused-rcp cell update (5 exp + 2 rcp per cell)
      half4v hpack;
      #pragma unroll
      for (int r = 0; r < 4; ++r) {
        float gi = fminf(fmaxf(acc[0][r], -20.f), 20.f);
        float gf = fminf(fmaxf(acc[1][r], -20.f), 20.f);
        float gg = fminf(fmaxf(acc[2][r], -10.f), 10.f);
        float go = fminf(fmaxf(acc[3][r], -20.f), 20.f);
        float Ae = __expf(-gf);
        float Be = __expf(-gi);
        float De = __expf(2.f * gg);
        float Ee = __expf(-go);
        float Dp = De + 1.f, Ap = Ae + 1.f, Bp = Be + 1.f;
        float Nn = cst[cg][r] * Bp * Dp + Ap * (De - 1.f);
        float cv = Nn * __builtin_amdgcn_rcpf(Ap * Bp * Dp);
        cst[cg][r] = cv;
        float cvc = fminf(fmaxf(cv, -10.f), 10.f);
        float Fe = __expf(2.f * cvc);
        hpack[r] = (_Float16)((Fe - 1.f) *
                   __builtin_amdgcn_rcpf((Ee + 1.f) * (Fe + 1.f)));
      }
      // write h into B-fragment position for the next step
      const int lp = nl + 16 * (2 * (cg & 1) + wq_hi);
      *(half4v*)&myscr[(cg >> 1) * 512 + lp * 8 + j0] = hpack;
    }
  }

  // epilogue: final h sits in scratch in B-frag order -> x1 = relu(h)
  #pragma unroll
  for (int kt = 0; kt < 4; ++kt) {
    const half8 hf = *(const half8*)&myscr[kt * 512 + ln * 8];
    float* dst = x1 + (size_t)(n0 + nl) * HDIM + kt * 32 + quad * 8;
    float4 o0, o1;
    o0.x = fmaxf((float)hf[0], 0.f); o0.y = fmaxf((float)hf[1], 0.f);
    o0.z = fmaxf((float)hf[2], 0.f); o0.w = fmaxf((float)hf[3], 0.f);
    o1.x = fmaxf((float)hf[4], 0.f); o1.y = fmaxf((float)hf[5], 0.f);
    o1.z = fmaxf((float)hf[6], 0.f); o1.w = fmaxf((float)hf[7], 0.f);
    *(float4*)dst = o0;
    *(float4*)(dst + 4) = o1;
  }
}

// ---------------------------------------------------------------------------
// Y[n][j] = sum_k X[n][k] * W[j][k].  32 nodes/block, W LDS-tiled in 64-row chunks.
template <int J>
__global__ __launch_bounds__(256) void gemm_xw(
    const float* __restrict__ X, const float* __restrict__ W, float* __restrict__ Y)
{
  __shared__ float Xs[32 * 132];
  __shared__ float Ws[64 * 132];
  const int tid = threadIdx.x;
  const int n0  = blockIdx.x * 32;
  for (int i = tid; i < 32 * 128; i += 256) {
    int nn = i >> 7, k = i & 127;
    Xs[nn * 132 + k] = X[(n0 + nn) * 128 + k];
  }
  const int nl = tid >> 3;
  const int jb = tid & 7;
  for (int c0 = 0; c0 < J; c0 += 64) {
    __syncthreads();
    for (int i = tid; i < 64 * 128; i += 256) {
      int r = i >> 7, k = i & 127;
      Ws[r * 132 + k] = W[(c0 + r) * 128 + k];
    }
    __syncthreads();
    float acc[8];
    #pragma unroll
    for (int m = 0; m < 8; ++m) acc[m] = 0.f;
    for (int k0 = 0; k0 < 128; k0 += 8) {
      float xr[8];
      #pragma unroll
      for (int r = 0; r < 8; ++r) xr[r] = Xs[nl * 132 + k0 + r];
      #pragma unroll
      for (int m = 0; m < 8; ++m) {
        const float* w = &Ws[(jb + (m << 3)) * 132 + k0];
        float a = acc[m];
        #pragma unroll
        for (int r = 0; r < 8; ++r) a += xr[r] * w[r];
        acc[m] = a;
      }
    }
    #pragma unroll
    for (int m = 0; m < 8; ++m)
      Y[(n0 + nl) * J + c0 + jb + (m << 3)] = acc[m];
  }
}

// ---------------------------------------------------------------------------
__global__ void zero_kernel(float* __restrict__ deg, int* __restrict__ cnt,
                            float* __restrict__ accum)
{
  int i = blockIdx.x * 256 + threadIdx.x;
  if (i < N_NODES) { deg[i] = 0.f; cnt[i] = 0; }
  if (i < JOUT) accum[i] = 0.f;
}

__global__ void count_kernel(const int* __restrict__ ei, const float* __restrict__ ew,
                             int* __restrict__ cnt, float* __restrict__ deg)
{
  int e = blockIdx.x * 256 + threadIdx.x;
  int c = ei[N_EDGES + e];
  atomicAdd(&cnt[c], 1);
  atomicAdd(&deg[c], ew[e]);
}

// shuffle-based exclusive scan: thread t owns elements [t*20, t*20+20).
__global__ __launch_bounds__(1024) void scan_kernel(
    const int* __restrict__ cnt, int* __restrict__ rowptr, int* __restrict__ cursor,
    const float* __restrict__ deg, float* __restrict__ dinv)
{
  const int tid  = threadIdx.x;
  const int lane = tid & 63;
  const int wv   = tid >> 6;        // 16 waves
  const int base = tid * 20;
  int vals[20];
  int sum = 0;
  if (tid < 1000) {
    #pragma unroll
    for (int j = 0; j < 20; ++j) { vals[j] = sum; sum += cnt[base + j]; }
  }
  int inc = sum;
  #pragma unroll
  for (int off = 1; off < 64; off <<= 1) {
    int t = __shfl_up(inc, off);
    if (lane >= off) inc += t;
  }
  __shared__ int wtot[16];
  __shared__ int wpre[16];
  if (lane == 63) wtot[wv] = inc;
  __syncthreads();
  if (tid == 0) {
    int s = 0;
    for (int i = 0; i < 16; ++i) { wpre[i] = s; s += wtot[i]; }
    rowptr[N_NODES] = s;
  }
  __syncthreads();
  if (tid < 1000) {
    int off = wpre[wv] + (inc - sum);
    #pragma unroll
    for (int j = 0; j < 20; ++j) {
      int v = off + vals[j];
      rowptr[base + j] = v;
      cursor[base + j] = v;
    }
  }
  for (int i = tid; i < N_NODES; i += 1024)
    dinv[i] = rsqrtf(deg[i] + 1.0f);   // +1 = self-loop weight
}

__global__ void fill_kernel(const int* __restrict__ ei, const float* __restrict__ ew,
                            const float* __restrict__ dinv, int* __restrict__ cursor,
                            int* __restrict__ esrc, float* __restrict__ ewn)
{
  int e = blockIdx.x * 256 + threadIdx.x;
  int r = ei[e];
  int c = ei[N_EDGES + e];
  int p = atomicAdd(&cursor[c], 1);
  esrc[p] = r;
  ewn[p]  = ew[e] * dinv[r];   // pre-scale by dinv[row]
}

// ---------------------------------------------------------------------------
// GCN aggregation: one wave per destination node; 64-edge tiles staged in LDS,
// broadcast loop unrolled x4. x2 = relu(agg + b).
__global__ __launch_bounds__(256) void gcn_agg_kernel(
    const float* __restrict__ y, const float* __restrict__ dinv,
    const int* __restrict__ rowptr, const int* __restrict__ esrc,
    const float* __restrict__ ewn, const float* __restrict__ gcn_b,
    float* __restrict__ x2)
{
  __shared__ float2 stg[4][64];
  const int lane = threadIdx.x & 63;
  const int wv = threadIdx.x >> 6;
  const int c = blockIdx.x * 4 + wv;
  const float dc = dinv[c];
  const float2* y2 = (const float2*)y;
  float2 yc = y2[c * 64 + lane];
  float ax = yc.x * dc * dc, ay = yc.y * dc * dc;   // self-loop term
  const int e0 = rowptr[c], e1 = rowptr[c + 1];
  for (int tb = e0; tb < e1; tb += 64) {
    const int cnt = min(64, e1 - tb);
    const int k = tb + lane;
    if (k < e1) stg[wv][lane] = make_float2(__int_as_float(esrc[k]), ewn[k] * dc);
    __builtin_amdgcn_wave_barrier();
    int i = 0;
    for (; i + 4 <= cnt; i += 4) {
      float2 p0 = stg[wv][i],     p1 = stg[wv][i + 1];
      float2 p2 = stg[wv][i + 2], p3 = stg[wv][i + 3];
      const float2 a0 = y2[(size_t)__float_as_int(p0.x) * 64 + lane];
      const float2 a1 = y2[(size_t)__float_as_int(p1.x) * 64 + lane];
      const float2 a2 = y2[(size_t)__float_as_int(p2.x) * 64 + lane];
      const float2 a3 = y2[(size_t)__float_as_int(p3.x) * 64 + lane];
      ax += a0.x * p0.y + a1.x * p1.y + a2.x * p2.y + a3.x * p3.y;
      ay += a0.y * p0.y + a1.y * p1.y + a2.y * p2.y + a3.y * p3.y;
    }
    for (; i < cnt; ++i) {
      float2 p0 = stg[wv][i];
      const float2 a0 = y2[(size_t)__float_as_int(p0.x) * 64 + lane];
      ax += a0.x * p0.y; ay += a0.y * p0.y;
    }
    __builtin_amdgcn_wave_barrier();
  }
  int j0 = lane * 2;
  x2[c * 128 + j0]     = fmaxf(ax + gcn_b[j0], 0.f);
  x2[c * 128 + j0 + 1] = fmaxf(ay + gcn_b[j0 + 1], 0.f);
}

// ---------------------------------------------------------------------------
// Per-node attention logits: a_src/a_dst [N][4] (padded float4)
__global__ __launch_bounds__(256) void gat_att_kernel(
    const float* __restrict__ xh, const float* __restrict__ att_src,
    const float* __restrict__ att_dst, float4* __restrict__ asrc,
    float4* __restrict__ adst)
{
  const int lane = threadIdx.x & 63;
  const int nd = blockIdx.x * 4 + (threadIdx.x >> 6);
  float s[3], d[3];
  #pragma unroll
  for (int h = 0; h < 3; ++h) {
    float xv = xh[nd * JOUT + h * 64 + lane];
    s[h] = xv * att_src[h * 64 + lane];
    d[h] = xv * att_dst[h * 64 + lane];
  }
  #pragma unroll
  for (int off = 1; off < 64; off <<= 1) {
    #pragma unroll
    for (int h = 0; h < 3; ++h) {
      s[h] += __shfl_xor(s[h], off);
      d[h] += __shfl_xor(d[h], off);
    }
  }
  if (lane == 0) {
    asrc[nd] = make_float4(s[0], s[1], s[2], 0.f);
    adst[nd] = make_float4(d[0], d[1], d[2], 0.f);
  }
}

// GAT: softmax over incoming edges (incl self-loop) + weighted agg.
// One wave per node; first-tile alpha cached in regs; 64-edge LDS-staged tiles.
__global__ __launch_bounds__(256) void gat_agg_kernel(
    const float* __restrict__ xh, const float4* __restrict__ asrc,
    const float4* __restrict__ adst, const int* __restrict__ rowptr,
    const int* __restrict__ esrc, float* __restrict__ accum)
{
  __shared__ float4 cstg[4][64];
  const int lane = threadIdx.x & 63;
  const int wv = threadIdx.x >> 6;
  const int c = blockIdx.x * 4 + wv;
  const int e0 = rowptr[c], e1 = rowptr[c + 1];
  float4 adc = adst[c];
  float4 asc = asrc[c];
  float self0 = lrelu(asc.x + adc.x);
  float self1 = lrelu(asc.y + adc.y);
  float self2 = lrelu(asc.z + adc.z);

  const bool has = (e0 + lane < e1);
  int s_first = 0;
  float v0 = -3.0e38f, v1 = -3.0e38f, v2 = -3.0e38f;
  if (has) {
    s_first = esrc[e0 + lane];
    float4 av = asrc[s_first];
    v0 = lrelu(av.x + adc.x);
    v1 = lrelu(av.y + adc.y);
    v2 = lrelu(av.z + adc.z);
  }
  float m0 = fmaxf(self0, v0), m1 = fmaxf(self1, v1), m2 = fmaxf(self2, v2);
  for (int k = e0 + 64 + lane; k < e1; k += 64) {
    float4 av = asrc[esrc[k]];
    m0 = fmaxf(m0, lrelu(av.x + adc.x));
    m1 = fmaxf(m1, lrelu(av.y + adc.y));
    m2 = fmaxf(m2, lrelu(av.z + adc.z));
  }
  #pragma unroll
  for (int off = 1; off < 64; off <<= 1) {
    m0 = fmaxf(m0, __shfl_xor(m0, off));
    m1 = fmaxf(m1, __shfl_xor(m1, off));
    m2 = fmaxf(m2, __shfl_xor(m2, off));
  }
  float ex0 = has ? __expf(v0 - m0) : 0.f;
  float ex1 = has ? __expf(v1 - m1) : 0.f;
  float ex2 = has ? __expf(v2 - m2) : 0.f;
  float d0 = ex0, d1 = ex1, d2 = ex2;
  for (int k = e0 + 64 + lane; k < e1; k += 64) {
    float4 av = asrc[esrc[k]];
    d0 += __expf(lrelu(av.x + adc.x) - m0);
    d1 += __expf(lrelu(av.y + adc.y) - m1);
    d2 += __expf(lrelu(av.z + adc.z) - m2);
  }
  #pragma unroll
  for (int off = 1; off < 64; off <<= 1) {
    d0 += __shfl_xor(d0, off);
    d1 += __shfl_xor(d1, off);
    d2 += __shfl_xor(d2, off);
  }
  float se0 = __expf(self0 - m0), se1 = __expf(self1 - m1), se2 = __expf(self2 - m2);
  d0 += se0; d1 += se1; d2 += se2;
  float iv0 = 1.f / d0, iv1 = 1.f / d1, iv2 = 1.f / d2;

  float o0 = se0 * iv0 * xh[c * JOUT + lane];
  float o1 = se1 * iv1 * xh[c * JOUT + 64 + lane];
  float o2 = se2 * iv2 * xh[c * JOUT + 128 + lane];

  for (int tb = e0; tb < e1; tb += 64) {
    const int cnt = min(64, e1 - tb);
    if (tb == e0) {
      if (has)
        cstg[wv][lane] = make_float4(__int_as_float(s_first),
                                     ex0 * iv0, ex1 * iv1, ex2 * iv2);
    } else {
      const int k = tb + lane;
      if (k < e1) {
        int s = esrc[k];
        float4 av = asrc[s];
        cstg[wv][lane] = make_float4(__int_as_float(s),
            __expf(lrelu(av.x + adc.x) - m0) * iv0,
            __expf(lrelu(av.y + adc.y) - m1) * iv1,
            __expf(lrelu(av.z + adc.z) - m2) * iv2);
      }
    }
    __builtin_amdgcn_wave_barrier();
    int i = 0;
    for (; i + 2 <= cnt; i += 2) {
      float4 q0 = cstg[wv][i], q1 = cstg[wv][i + 1];
      const float* r0 = xh + (size_t)__float_as_int(q0.x) * JOUT;
      const float* r1 = xh + (size_t)__float_as_int(q1.x) * JOUT;
      float a0 = r0[lane], b0 = r0[64 + lane], g0 = r0[128 + lane];
      float a1 = r1[lane], b1 = r1[64 + lane], g1 = r1[128 + lane];
      o0 += q0.y * a0 + q1.y * a1;
      o1 += q0.z * b0 + q1.z * b1;
      o2 += q0.w * g0 + q1.w * g1;
    }
    for (; i < cnt; ++i) {
      float4 q0 = cstg[wv][i];
      const float* r0 = xh + (size_t)__float_as_int(q0.x) * JOUT;
      o0 += q0.y * r0[lane];
      o1 += q0.z * r0[64 + lane];
      o2 += q0.w * r0[128 + lane];
    }
    __builtin_amdgcn_wave_barrier();
  }

  __shared__ float red[4][JOUT];
  red[wv][lane]       = o0;
  red[wv][64 + lane]  = o1;
  red[wv][128 + lane] = o2;
  __syncthreads();
  if (threadIdx.x < JOUT) {
    float sum = red[0][threadIdx.x] + red[1][threadIdx.x] +
                red[2][threadIdx.x] + red[3][threadIdx.x];
    atomicAdd(&accum[threadIdx.x], sum);
  }
}

__global__ void finalize_kernel(const float* __restrict__ accum,
                                const float* __restrict__ gat_b,
                                float* __restrict__ out)
{
  int j = threadIdx.x;
  if (j < JOUT) out[j] = accum[j] * (1.0f / N_NODES) + gat_b[j];
}

// ---------------------------------------------------------------------------
extern "C" void kernel_launch(void* const* d_in, const int* in_sizes, int n_in,
                              void* d_out, int out_size, void* d_ws, size_t ws_size,
                              hipStream_t stream)
{
  const float* xfeat = (const float*)d_in[0];
  const int*   eidx  = (const int*)d_in[1];
  const float* eattr = (const float*)d_in[2];
  const float* Wih   = (const float*)d_in[3];
  const float* Whh   = (const float*)d_in[4];
  const float* bihp  = (const float*)d_in[5];
  const float* bhhp  = (const float*)d_in[6];
  const float* gcnW  = (const float*)d_in[7];
  const float* gcnb  = (const float*)d_in[8];
  const float* gatW  = (const float*)d_in[9];
  const float* attS  = (const float*)d_in[10];
  const float* attD  = (const float*)d_in[11];
  const float* gatb  = (const float*)d_in[12];
  float* out = (float*)d_out;

  char* ws = (char*)d_ws;
  size_t off = 0;
  auto alloc = [&](size_t bytes) {
    char* p = ws + off;
    off += (bytes + 255) & ~size_t(255);
    return p;
  };
  float*     x1     = (float*)alloc((size_t)N_NODES * 128 * 4);
  float*     y      = (float*)alloc((size_t)N_NODES * 128 * 4);
  float*     x2     = (float*)alloc((size_t)N_NODES * 128 * 4);
  float*     xh     = (float*)alloc((size_t)N_NODES * 192 * 4);
  float4*    asrc   = (float4*)alloc((size_t)N_NODES * 16);
  float4*    adst   = (float4*)alloc((size_t)N_NODES * 16);
  float*     deg    = (float*)alloc((size_t)N_NODES * 4);
  float*     dinv   = (float*)alloc((size_t)N_NODES * 4);
  int*       cnt    = (int*)alloc((size_t)N_NODES * 4);
  int*       rowptr = (int*)alloc((size_t)(N_NODES + 1) * 4);
  int*       cursor = (int*)alloc((size_t)N_NODES * 4);
  int*       esrc   = (int*)alloc((size_t)N_EDGES * 4);
  float*     ewn    = (float*)alloc((size_t)N_EDGES * 4);
  float*     accum  = (float*)alloc(JOUT * 4);
  _Float16*  wpack  = (_Float16*)alloc(131072);

  // opt-in to >64KB dynamic LDS for the barrier-free LSTM (idempotent)
  hipFuncSetAttribute((const void*)lstm_stream_kernel,
                      hipFuncAttributeMaxDynamicSharedMemorySize, LDS_TOTAL);

  zero_kernel<<<(N_NODES + 255) / 256, 256, 0, stream>>>(deg, cnt, accum);
  pack_whh_kernel<<<32, 256, 0, stream>>>(Whh, wpack);
  lstm_stream_kernel<<<N_NODES / NBB, 320, LDS_TOTAL, stream>>>(
      xfeat, wpack, Wih, bihp, bhhp, x1);
  count_kernel<<<N_EDGES / 256, 256, 0, stream>>>(eidx, eattr, cnt, deg);
  scan_kernel<<<1, 1024, 0, stream>>>(cnt, rowptr, cursor, deg, dinv);
  fill_kernel<<<N_EDGES / 256, 256, 0, stream>>>(eidx, eattr, dinv, cursor, esrc, ewn);
  gemm_xw<128><<<N_NODES / 32, 256, 0, stream>>>(x1, gcnW, y);
  gcn_agg_kernel<<<N_NODES / 4, 256, 0, stream>>>(y, dinv, rowptr, esrc, ewn, gcnb, x2);
  gemm_xw<192><<<N_NODES / 32, 256, 0, stream>>>(x2, gatW, xh);
  gat_att_kernel<<<N_NODES / 4, 256, 0, stream>>>(xh, attS, attD, asrc, adst);
  gat_agg_kernel<<<N_NODES / 4, 256, 0, stream>>>(xh, asrc, adst, rowptr, esrc, accum);
  finalize_kernel<<<1, 256, 0, stream>>>(accum, gatb, out);
}

// Round 14
// 1016.969 us; speedup vs baseline: 3.3369x; 3.3369x over previous
//
#include <hip/hip_runtime.h>

// TemporalGAT: LSTM(T=64,H=128) -> ReLU -> GCNConv -> ReLU -> GATConv(3x64) -> mean
// Round 14: r12 barrier-free structure + batched A-fragment loads.
// r13 failure: Af[2][cur] dynamic index -> scratch (16GB spill traffic, 3.1ms).
// r12 defect: load->MFMA distance 1 -> one ds_read in flight (~120cyc x16/cg).
// Fix: STATIC-indexed Afr[16]; phase-split source (16 loads back-to-back, then
// init, then 16 MFMAs) -> one latency exposure per cg-group, fine-grained
// lgkmcnt lets MFMAs start while tail loads drain. ~180 regs, no spill.

#define N_NODES 20000
#define T_STEPS 64
#define N_EDGES 640000
#define HDIM    128
#define JOUT    192   // HEADS*OUT = 3*64
#define NEG_SLOPE 0.2f
#define NBW     16    // nodes per wave
#define WAVES   5
#define NBB     (NBW * WAVES)   // 80 nodes per block
#define LDS_W     131072                  // packed Whh fp16
#define LDS_BW    4096                    // (bias, wih) float2[512]
#define LDS_SCR   (WAVES * 4096)          // per-wave h scratch
#define LDS_TOTAL (LDS_W + LDS_BW + LDS_SCR)   // 155648

typedef _Float16 half8 __attribute__((ext_vector_type(8)));
typedef _Float16 half4v __attribute__((ext_vector_type(4)));
typedef float floatx4 __attribute__((ext_vector_type(4)));

__device__ __forceinline__ float lrelu(float x) { return x > 0.f ? x : NEG_SLOPE * x; }

// ---------------------------------------------------------------------------
// Pre-pack Whh (fp32 [512][128]) into fp16 MFMA A-fragment order:
// frag i = (tile = nt*4+kt, lane): 8 halves = Whh[nt*16 + (lane&15)][kt*32 + (lane>>4)*8 + j]
__global__ void pack_whh_kernel(const float* __restrict__ Whh,
                                _Float16* __restrict__ Wpack)
{
  int i = blockIdx.x * 256 + threadIdx.x;   // 0..8191
  int tile = i >> 6, lane = i & 63;
  int nt = tile >> 2, kt = tile & 3;
  int row = nt * 16 + (lane & 15);
  int c0  = kt * 32 + (lane >> 4) * 8;
  half8 v;
  #pragma unroll
  for (int j = 0; j < 8; ++j)
    v[j] = (_Float16)Whh[row * 128 + c0 + j];
  *(half8*)&Wpack[(size_t)i * 8] = v;
}

// ---------------------------------------------------------------------------
// Barrier-free LSTM. Block = 320 threads (5 waves), 80 nodes. Wave w owns nodes
// n0+w*16..+15 and computes all 512 gate rows per step:
//   G^T[gate][node] = Whh(A, LDS frags) x h(B, regs)  via 128 MFMAs/step.
// Per cg-group: 16 batched ds_read_b128 (static Afr[16]), bias init, 16 MFMAs,
// fused-rcp update, h write to wave-private scratch. No block barriers in loop.
__global__ __launch_bounds__(320, 1) void lstm_stream_kernel(
    const float* __restrict__ xfeat, const _Float16* __restrict__ Wpack,
    const float* __restrict__ Wih, const float* __restrict__ bih,
    const float* __restrict__ bhh, float* __restrict__ x1)
{
  extern __shared__ char dynlds[];
  _Float16* Wl  = (_Float16*)dynlds;                    // [128 tiles][64 lanes][8]
  float2*   bw  = (float2*)(dynlds + LDS_W);            // [512] (bias, wih)
  _Float16* scr = (_Float16*)(dynlds + LDS_W + LDS_BW); // [5][2048]

  const int tid  = threadIdx.x;   // 0..319
  const int w    = tid >> 6;      // wave 0..4
  const int ln   = tid & 63;
  const int nl   = ln & 15;       // node within wave
  const int quad = ln >> 4;
  const int n0   = blockIdx.x * NBB + w * NBW;

  // stage packed Whh -> LDS (coalesced float4)
  {
    const float4* src = (const float4*)Wpack;
    float4* dst = (float4*)Wl;
    for (int i = tid; i < LDS_W / 16; i += 320) dst[i] = src[i];
  }
  for (int i = tid; i < 512; i += 320)
    bw[i] = make_float2(bih[i] + bhh[i], Wih[i]);
  {
    float4* z = (float4*)scr;
    for (int i = tid; i < LDS_SCR / 16; i += 320)
      z[i] = make_float4(0.f, 0.f, 0.f, 0.f);
  }
  __syncthreads();   // the ONLY block barrier

  _Float16* myscr = scr + w * 2048;
  const float* xrow = xfeat + (size_t)(n0 + nl) * T_STEPS;

  float cst[8][4];
  #pragma unroll
  for (int cg = 0; cg < 8; ++cg)
    #pragma unroll
    for (int r = 0; r < 4; ++r) cst[cg][r] = 0.f;

  const int wq_hi = quad >> 1;
  const int j0    = (quad & 1) * 4;

  #pragma unroll 1
  for (int t = 0; t < T_STEPS; ++t) {
    // h of previous step as B-fragments (wave-private scratch, seq addresses)
    half8 Bf[4];
    #pragma unroll
    for (int kt = 0; kt < 4; ++kt)
      Bf[kt] = *(const half8*)&myscr[kt * 512 + ln * 8];
    const float xv = xrow[t];

    #pragma unroll 1
    for (int cg = 0; cg < 8; ++cg) {
      // phase 1: issue ALL 16 A-fragment loads back-to-back (static indices)
      half8 Afr[16];
      #pragma unroll
      for (int kt = 0; kt < 4; ++kt)
        #pragma unroll
        for (int g = 0; g < 4; ++g)
          Afr[kt * 4 + g] =
              *(const half8*)&Wl[(size_t)(((g * 8 + cg) * 4 + kt) * 64 + ln) * 8];
      // phase 2: init gates (bias + x*Wih) while loads drain
      floatx4 acc[4];
      #pragma unroll
      for (int g = 0; g < 4; ++g) {
        const int base = g * 128 + cg * 16 + quad * 4;
        const float4 p0 = *(const float4*)&bw[base];
        const float4 p1 = *(const float4*)&bw[base + 2];
        acc[g][0] = p0.x + xv * p0.y;
        acc[g][1] = p0.z + xv * p0.w;
        acc[g][2] = p1.x + xv * p1.y;
        acc[g][3] = p1.z + xv * p1.w;
      }
      // phase 3: 16 MFMAs on the batch (fine-grained lgkmcnt from compiler)
      #pragma unroll
      for (int kt = 0; kt < 4; ++kt)
        #pragma unroll
        for (int g = 0; g < 4; ++g)
          acc[g] = __builtin_amdgcn_mfma_f32_16x16x32_f16(
              Afr[kt * 4 + g], Bf[kt], acc[g], 0, 0, 0);
      // phase 4: fused-rcp cell update (5 exp + 2 rcp per cell)
      half4v hpack;
      #pragma unroll
      for (int r = 0; r < 4; ++r) {
        float gi = fminf(fmaxf(acc[0][r], -20.f), 20.f);
        float gf = fminf(fmaxf(acc[1][r], -20.f), 20.f);
        float gg = fminf(fmaxf(acc[2][r], -10.f), 10.f);
        float go = fminf(fmaxf(acc[3][r], -20.f), 20.f);
        float Ae = __expf(-gf);
        float Be = __expf(-gi);
        float De = __expf(2.f * gg);
        float Ee = __expf(-go);
        float Dp = De + 1.f, Ap = Ae + 1.f, Bp = Be + 1.f;
        float Nn = cst[cg][r] * Bp * Dp + Ap * (De - 1.f);
        float cv = Nn * __builtin_amdgcn_rcpf(Ap * Bp * Dp);
        cst[cg][r] = cv;
        float cvc = fminf(fmaxf(cv, -10.f), 10.f);
        float Fe = __expf(2.f * cvc);
        hpack[r] = (_Float16)((Fe - 1.f) *
                   __builtin_amdgcn_rcpf((Ee + 1.f) * (Fe + 1.f)));
      }
      // write h into B-fragment position for the next step
      const int lp = nl + 16 * (2 * (cg & 1) + wq_hi);
      *(half4v*)&myscr[(cg >> 1) * 512 + lp * 8 + j0] = hpack;
    }
  }

  // epilogue: final h sits in scratch in B-frag order -> x1 = relu(h)
  #pragma unroll
  for (int kt = 0; kt < 4; ++kt) {
    const half8 hf = *(const half8*)&myscr[kt * 512 + ln * 8];
    float* dst = x1 + (size_t)(n0 + nl) * HDIM + kt * 32 + quad * 8;
    float4 o0, o1;
    o0.x = fmaxf((float)hf[0], 0.f); o0.y = fmaxf((float)hf[1], 0.f);
    o0.z = fmaxf((float)hf[2], 0.f); o0.w = fmaxf((float)hf[3], 0.f);
    o1.x = fmaxf((float)hf[4], 0.f); o1.y = fmaxf((float)hf[5], 0.f);
    o1.z = fmaxf((float)hf[6], 0.f); o1.w = fmaxf((float)hf[7], 0.f);
    *(float4*)dst = o0;
    *(float4*)(dst + 4) = o1;
  }
}

// ---------------------------------------------------------------------------
// Y[n][j] = sum_k X[n][k] * W[j][k].  32 nodes/block, W LDS-tiled in 64-row chunks.
template <int J>
__global__ __launch_bounds__(256) void gemm_xw(
    const float* __restrict__ X, const float* __restrict__ W, float* __restrict__ Y)
{
  __shared__ float Xs[32 * 132];
  __shared__ float Ws[64 * 132];
  const int tid = threadIdx.x;
  const int n0  = blockIdx.x * 32;
  for (int i = tid; i < 32 * 128; i += 256) {
    int nn = i >> 7, k = i & 127;
    Xs[nn * 132 + k] = X[(n0 + nn) * 128 + k];
  }
  const int nl = tid >> 3;
  const int jb = tid & 7;
  for (int c0 = 0; c0 < J; c0 += 64) {
    __syncthreads();
    for (int i = tid; i < 64 * 128; i += 256) {
      int r = i >> 7, k = i & 127;
      Ws[r * 132 + k] = W[(c0 + r) * 128 + k];
    }
    __syncthreads();
    float acc[8];
    #pragma unroll
    for (int m = 0; m < 8; ++m) acc[m] = 0.f;
    for (int k0 = 0; k0 < 128; k0 += 8) {
      float xr[8];
      #pragma unroll
      for (int r = 0; r < 8; ++r) xr[r] = Xs[nl * 132 + k0 + r];
      #pragma unroll
      for (int m = 0; m < 8; ++m) {
        const float* w = &Ws[(jb + (m << 3)) * 132 + k0];
        float a = acc[m];
        #pragma unroll
        for (int r = 0; r < 8; ++r) a += xr[r] * w[r];
        acc[m] = a;
      }
    }
    #pragma unroll
    for (int m = 0; m < 8; ++m)
      Y[(n0 + nl) * J + c0 + jb + (m << 3)] = acc[m];
  }
}

// ---------------------------------------------------------------------------
__global__ void zero_kernel(float* __restrict__ deg, int* __restrict__ cnt,
                            float* __restrict__ accum)
{
  int i = blockIdx.x * 256 + threadIdx.x;
  if (i < N_NODES) { deg[i] = 0.f; cnt[i] = 0; }
  if (i < JOUT) accum[i] = 0.f;
}

__global__ void count_kernel(const int* __restrict__ ei, const float* __restrict__ ew,
                             int* __restrict__ cnt, float* __restrict__ deg)
{
  int e = blockIdx.x * 256 + threadIdx.x;
  int c = ei[N_EDGES + e];
  atomicAdd(&cnt[c], 1);
  atomicAdd(&deg[c], ew[e]);
}

// shuffle-based exclusive scan: thread t owns elements [t*20, t*20+20).
__global__ __launch_bounds__(1024) void scan_kernel(
    const int* __restrict__ cnt, int* __restrict__ rowptr, int* __restrict__ cursor,
    const float* __restrict__ deg, float* __restrict__ dinv)
{
  const int tid  = threadIdx.x;
  const int lane = tid & 63;
  const int wv   = tid >> 6;        // 16 waves
  const int base = tid * 20;
  int vals[20];
  int sum = 0;
  if (tid < 1000) {
    #pragma unroll
    for (int j = 0; j < 20; ++j) { vals[j] = sum; sum += cnt[base + j]; }
  }
  int inc = sum;
  #pragma unroll
  for (int off = 1; off < 64; off <<= 1) {
    int t = __shfl_up(inc, off);
    if (lane >= off) inc += t;
  }
  __shared__ int wtot[16];
  __shared__ int wpre[16];
  if (lane == 63) wtot[wv] = inc;
  __syncthreads();
  if (tid == 0) {
    int s = 0;
    for (int i = 0; i < 16; ++i) { wpre[i] = s; s += wtot[i]; }
    rowptr[N_NODES] = s;
  }
  __syncthreads();
  if (tid < 1000) {
    int off = wpre[wv] + (inc - sum);
    #pragma unroll
    for (int j = 0; j < 20; ++j) {
      int v = off + vals[j];
      rowptr[base + j] = v;
      cursor[base + j] = v;
    }
  }
  for (int i = tid; i < N_NODES; i += 1024)
    dinv[i] = rsqrtf(deg[i] + 1.0f);   // +1 = self-loop weight
}

__global__ void fill_kernel(const int* __restrict__ ei, const float* __restrict__ ew,
                            const float* __restrict__ dinv, int* __restrict__ cursor,
                            int* __restrict__ esrc, float* __restrict__ ewn)
{
  int e = blockIdx.x * 256 + threadIdx.x;
  int r = ei[e];
  int c = ei[N_EDGES + e];
  int p = atomicAdd(&cursor[c], 1);
  esrc[p] = r;
  ewn[p]  = ew[e] * dinv[r];   // pre-scale by dinv[row]
}

// ---------------------------------------------------------------------------
// GCN aggregation: one wave per destination node; 64-edge tiles staged in LDS,
// broadcast loop unrolled x4. x2 = relu(agg + b).
__global__ __launch_bounds__(256) void gcn_agg_kernel(
    const float* __restrict__ y, const float* __restrict__ dinv,
    const int* __restrict__ rowptr, const int* __restrict__ esrc,
    const float* __restrict__ ewn, const float* __restrict__ gcn_b,
    float* __restrict__ x2)
{
  __shared__ float2 stg[4][64];
  const int lane = threadIdx.x & 63;
  const int wv = threadIdx.x >> 6;
  const int c = blockIdx.x * 4 + wv;
  const float dc = dinv[c];
  const float2* y2 = (const float2*)y;
  float2 yc = y2[c * 64 + lane];
  float ax = yc.x * dc * dc, ay = yc.y * dc * dc;   // self-loop term
  const int e0 = rowptr[c], e1 = rowptr[c + 1];
  for (int tb = e0; tb < e1; tb += 64) {
    const int cnt = min(64, e1 - tb);
    const int k = tb + lane;
    if (k < e1) stg[wv][lane] = make_float2(__int_as_float(esrc[k]), ewn[k] * dc);
    __builtin_amdgcn_wave_barrier();
    int i = 0;
    for (; i + 4 <= cnt; i += 4) {
      float2 p0 = stg[wv][i],     p1 = stg[wv][i + 1];
      float2 p2 = stg[wv][i + 2], p3 = stg[wv][i + 3];
      const float2 a0 = y2[(size_t)__float_as_int(p0.x) * 64 + lane];
      const float2 a1 = y2[(size_t)__float_as_int(p1.x) * 64 + lane];
      const float2 a2 = y2[(size_t)__float_as_int(p2.x) * 64 + lane];
      const float2 a3 = y2[(size_t)__float_as_int(p3.x) * 64 + lane];
      ax += a0.x * p0.y + a1.x * p1.y + a2.x * p2.y + a3.x * p3.y;
      ay += a0.y * p0.y + a1.y * p1.y + a2.y * p2.y + a3.y * p3.y;
    }
    for (; i < cnt; ++i) {
      float2 p0 = stg[wv][i];
      const float2 a0 = y2[(size_t)__float_as_int(p0.x) * 64 + lane];
      ax += a0.x * p0.y; ay += a0.y * p0.y;
    }
    __builtin_amdgcn_wave_barrier();
  }
  int j0 = lane * 2;
  x2[c * 128 + j0]     = fmaxf(ax + gcn_b[j0], 0.f);
  x2[c * 128 + j0 + 1] = fmaxf(ay + gcn_b[j0 + 1], 0.f);
}

// ---------------------------------------------------------------------------
// Per-node attention logits: a_src/a_dst [N][4] (padded float4)
__global__ __launch_bounds__(256) void gat_att_kernel(
    const float* __restrict__ xh, const float* __restrict__ att_src,
    const float* __restrict__ att_dst, float4* __restrict__ asrc,
    float4* __restrict__ adst)
{
  const int lane = threadIdx.x & 63;
  const int nd = blockIdx.x * 4 + (threadIdx.x >> 6);
  float s[3], d[3];
  #pragma unroll
  for (int h = 0; h < 3; ++h) {
    float xv = xh[nd * JOUT + h * 64 + lane];
    s[h] = xv * att_src[h * 64 + lane];
    d[h] = xv * att_dst[h * 64 + lane];
  }
  #pragma unroll
  for (int off = 1; off < 64; off <<= 1) {
    #pragma unroll
    for (int h = 0; h < 3; ++h) {
      s[h] += __shfl_xor(s[h], off);
      d[h] += __shfl_xor(d[h], off);
    }
  }
  if (lane == 0) {
    asrc[nd] = make_float4(s[0], s[1], s[2], 0.f);
    adst[nd] = make_float4(d[0], d[1], d[2], 0.f);
  }
}

// GAT: softmax over incoming edges (incl self-loop) + weighted agg.
// One wave per node; first-tile alpha cached in regs; 64-edge LDS-staged tiles.
__global__ __launch_bounds__(256) void gat_agg_kernel(
    const float* __restrict__ xh, const float4* __restrict__ asrc,
    const float4* __restrict__ adst, const int* __restrict__ rowptr,
    const int* __restrict__ esrc, float* __restrict__ accum)
{
  __shared__ float4 cstg[4][64];
  const int lane = threadIdx.x & 63;
  const int wv = threadIdx.x >> 6;
  const int c = blockIdx.x * 4 + wv;
  const int e0 = rowptr[c], e1 = rowptr[c + 1];
  float4 adc = adst[c];
  float4 asc = asrc[c];
  float self0 = lrelu(asc.x + adc.x);
  float self1 = lrelu(asc.y + adc.y);
  float self2 = lrelu(asc.z + adc.z);

  const bool has = (e0 + lane < e1);
  int s_first = 0;
  float v0 = -3.0e38f, v1 = -3.0e38f, v2 = -3.0e38f;
  if (has) {
    s_first = esrc[e0 + lane];
    float4 av = asrc[s_first];
    v0 = lrelu(av.x + adc.x);
    v1 = lrelu(av.y + adc.y);
    v2 = lrelu(av.z + adc.z);
  }
  float m0 = fmaxf(self0, v0), m1 = fmaxf(self1, v1), m2 = fmaxf(self2, v2);
  for (int k = e0 + 64 + lane; k < e1; k += 64) {
    float4 av = asrc[esrc[k]];
    m0 = fmaxf(m0, lrelu(av.x + adc.x));
    m1 = fmaxf(m1, lrelu(av.y + adc.y));
    m2 = fmaxf(m2, lrelu(av.z + adc.z));
  }
  #pragma unroll
  for (int off = 1; off < 64; off <<= 1) {
    m0 = fmaxf(m0, __shfl_xor(m0, off));
    m1 = fmaxf(m1, __shfl_xor(m1, off));
    m2 = fmaxf(m2, __shfl_xor(m2, off));
  }
  float ex0 = has ? __expf(v0 - m0) : 0.f;
  float ex1 = has ? __expf(v1 - m1) : 0.f;
  float ex2 = has ? __expf(v2 - m2) : 0.f;
  float d0 = ex0, d1 = ex1, d2 = ex2;
  for (int k = e0 + 64 + lane; k < e1; k += 64) {
    float4 av = asrc[esrc[k]];
    d0 += __expf(lrelu(av.x + adc.x) - m0);
    d1 += __expf(lrelu(av.y + adc.y) - m1);
    d2 += __expf(lrelu(av.z + adc.z) - m2);
  }
  #pragma unroll
  for (int off = 1; off < 64; off <<= 1) {
    d0 += __shfl_xor(d0, off);
    d1 += __shfl_xor(d1, off);
    d2 += __shfl_xor(d2, off);
  }
  float se0 = __expf(self0 - m0), se1 = __expf(self1 - m1), se2 = __expf(self2 - m2);
  d0 += se0; d1 += se1; d2 += se2;
  float iv0 = 1.f / d0, iv1 = 1.f / d1, iv2 = 1.f / d2;

  float o0 = se0 * iv0 * xh[c * JOUT + lane];
  float o1 = se1 * iv1 * xh[c * JOUT + 64 + lane];
  float o2 = se2 * iv2 * xh[c * JOUT + 128 + lane];

  for (int tb = e0; tb < e1; tb += 64) {
    const int cnt = min(64, e1 - tb);
    if (tb == e0) {
      if (has)
        cstg[wv][lane] = make_float4(__int_as_float(s_first),
                                     ex0 * iv0, ex1 * iv1, ex2 * iv2);
    } else {
      const int k = tb + lane;
      if (k < e1) {
        int s = esrc[k];
        float4 av = asrc[s];
        cstg[wv][lane] = make_float4(__int_as_float(s),
            __expf(lrelu(av.x + adc.x) - m0) * iv0,
            __expf(lrelu(av.y + adc.y) - m1) * iv1,
            __expf(lrelu(av.z + adc.z) - m2) * iv2);
      }
    }
    __builtin_amdgcn_wave_barrier();
    int i = 0;
    for (; i + 2 <= cnt; i += 2) {
      float4 q0 = cstg[wv][i], q1 = cstg[wv][i + 1];
      const float* r0 = xh + (size_t)__float_as_int(q0.x) * JOUT;
      const float* r1 = xh + (size_t)__float_as_int(q1.x) * JOUT;
      float a0 = r0[lane], b0 = r0[64 + lane], g0 = r0[128 + lane];
      float a1 = r1[lane], b1 = r1[64 + lane], g1 = r1[128 + lane];
      o0 += q0.y * a0 + q1.y * a1;
      o1 += q0.z * b0 + q1.z * b1;
      o2 += q0.w * g0 + q1.w * g1;
    }
    for (; i < cnt; ++i) {
      float4 q0 = cstg[wv][i];
      const float* r0 = xh + (size_t)__float_as_int(q0.x) * JOUT;
      o0 += q0.y * r0[lane];
      o1 += q0.z * r0[64 + lane];
      o2 += q0.w * r0[128 + lane];
    }
    __builtin_amdgcn_wave_barrier();
  }

  __shared__ float red[4][JOUT];
  red[wv][lane]       = o0;
  red[wv][64 + lane]  = o1;
  red[wv][128 + lane] = o2;
  __syncthreads();
  if (threadIdx.x < JOUT) {
    float sum = red[0][threadIdx.x] + red[1][threadIdx.x] +
                red[2][threadIdx.x] + red[3][threadIdx.x];
    atomicAdd(&accum[threadIdx.x], sum);
  }
}

__global__ void finalize_kernel(const float* __restrict__ accum,
                                const float* __restrict__ gat_b,
                                float* __restrict__ out)
{
  int j = threadIdx.x;
  if (j < JOUT) out[j] = accum[j] * (1.0f / N_NODES) + gat_b[j];
}

// ---------------------------------------------------------------------------
extern "C" void kernel_launch(void* const* d_in, const int* in_sizes, int n_in,
                              void* d_out, int out_size, void* d_ws, size_t ws_size,
                              hipStream_t stream)
{
  const float* xfeat = (const float*)d_in[0];
  const int*   eidx  = (const int*)d_in[1];
  const float* eattr = (const float*)d_in[2];
  const float* Wih   = (const float*)d_in[3];
  const float* Whh   = (const float*)d_in[4];
  const float* bihp  = (const float*)d_in[5];
  const float* bhhp  = (const float*)d_in[6];
  const float* gcnW  = (const float*)d_in[7];
  const float* gcnb  = (const float*)d_in[8];
  const float* gatW  = (const float*)d_in[9];
  const float* attS  = (const float*)d_in[10];
  const float* attD  = (const float*)d_in[11];
  const float* gatb  = (const float*)d_in[12];
  float* out = (float*)d_out;

  char* ws = (char*)d_ws;
  size_t off = 0;
  auto alloc = [&](size_t bytes) {
    char* p = ws + off;
    off += (bytes + 255) & ~size_t(255);
    return p;
  };
  float*     x1     = (float*)alloc((size_t)N_NODES * 128 * 4);
  float*     y      = (float*)alloc((size_t)N_NODES * 128 * 4);
  float*     x2     = (float*)alloc((size_t)N_NODES * 128 * 4);
  float*     xh     = (float*)alloc((size_t)N_NODES * 192 * 4);
  float4*    asrc   = (float4*)alloc((size_t)N_NODES * 16);
  float4*    adst   = (float4*)alloc((size_t)N_NODES * 16);
  float*     deg    = (float*)alloc((size_t)N_NODES * 4);
  float*     dinv   = (float*)alloc((size_t)N_NODES * 4);
  int*       cnt    = (int*)alloc((size_t)N_NODES * 4);
  int*       rowptr = (int*)alloc((size_t)(N_NODES + 1) * 4);
  int*       cursor = (int*)alloc((size_t)N_NODES * 4);
  int*       esrc   = (int*)alloc((size_t)N_EDGES * 4);
  float*     ewn    = (float*)alloc((size_t)N_EDGES * 4);
  float*     accum  = (float*)alloc(JOUT * 4);
  _Float16*  wpack  = (_Float16*)alloc(131072);

  // opt-in to >64KB dynamic LDS for the barrier-free LSTM (idempotent)
  hipFuncSetAttribute((const void*)lstm_stream_kernel,
                      hipFuncAttributeMaxDynamicSharedMemorySize, LDS_TOTAL);

  zero_kernel<<<(N_NODES + 255) / 256, 256, 0, stream>>>(deg, cnt, accum);
  pack_whh_kernel<<<32, 256, 0, stream>>>(Whh, wpack);
  lstm_stream_kernel<<<N_NODES / NBB, 320, LDS_TOTAL, stream>>>(
      xfeat, wpack, Wih, bihp, bhhp, x1);
  count_kernel<<<N_EDGES / 256, 256, 0, stream>>>(eidx, eattr, cnt, deg);
  scan_kernel<<<1, 1024, 0, stream>>>(cnt, rowptr, cursor, deg, dinv);
  fill_kernel<<<N_EDGES / 256, 256, 0, stream>>>(eidx, eattr, dinv, cursor, esrc, ewn);
  gemm_xw<128><<<N_NODES / 32, 256, 0, stream>>>(x1, gcnW, y);
  gcn_agg_kernel<<<N_NODES / 4, 256, 0, stream>>>(y, dinv, rowptr, esrc, ewn, gcnb, x2);
  gemm_xw<192><<<N_NODES / 32, 256, 0, stream>>>(x2, gatW, xh);
  gat_att_kernel<<<N_NODES / 4, 256, 0, stream>>>(xh, attS, attD, asrc, adst);
  gat_agg_kernel<<<N_NODES / 4, 256, 0, stream>>>(xh, asrc, adst, rowptr, esrc, accum);
  finalize_kernel<<<1, 256, 0, stream>>>(accum, gatb, out);
}

// Round 15
// 1011.859 us; speedup vs baseline: 3.3537x; 1.0050x over previous
//
#include <hip/hip_runtime.h>

// TemporalGAT: LSTM(T=64,H=128) -> ReLU -> GCNConv -> ReLU -> GATConv(3x64) -> mean
// Round 15: pin the A-fragment load schedule. r14 proved source order is not
// schedule order: the pressure-minimizing scheduler (which assumes max
// occupancy because dynamic LDS is invisible at compile time) re-sank the
// batched loads into a distance-1 serial chain (VGPR=64, same 603us as r12).
// Fix: (1) __builtin_amdgcn_sched_barrier(0) between load phase and MFMA
// phase -- hard fence, 16 ds_read_b128 forced in flight together;
// (2) amdgpu_waves_per_eu(1,2) grants the ~160-reg budget so the forced
// liveness allocates registers instead of spilling (r13 lesson).

#define N_NODES 20000
#define T_STEPS 64
#define N_EDGES 640000
#define HDIM    128
#define JOUT    192   // HEADS*OUT = 3*64
#define NEG_SLOPE 0.2f
#define NBW     16    // nodes per wave
#define WAVES   5
#define NBB     (NBW * WAVES)   // 80 nodes per block
#define LDS_W     131072                  // packed Whh fp16
#define LDS_BW    4096                    // (bias, wih) float2[512]
#define LDS_SCR   (WAVES * 4096)          // per-wave h scratch
#define LDS_TOTAL (LDS_W + LDS_BW + LDS_SCR)   // 155648

typedef _Float16 half8 __attribute__((ext_vector_type(8)));
typedef _Float16 half4v __attribute__((ext_vector_type(4)));
typedef float floatx4 __attribute__((ext_vector_type(4)));

__device__ __forceinline__ float lrelu(float x) { return x > 0.f ? x : NEG_SLOPE * x; }

// ---------------------------------------------------------------------------
// Pre-pack Whh (fp32 [512][128]) into fp16 MFMA A-fragment order:
// frag i = (tile = nt*4+kt, lane): 8 halves = Whh[nt*16 + (lane&15)][kt*32 + (lane>>4)*8 + j]
__global__ void pack_whh_kernel(const float* __restrict__ Whh,
                                _Float16* __restrict__ Wpack)
{
  int i = blockIdx.x * 256 + threadIdx.x;   // 0..8191
  int tile = i >> 6, lane = i & 63;
  int nt = tile >> 2, kt = tile & 3;
  int row = nt * 16 + (lane & 15);
  int c0  = kt * 32 + (lane >> 4) * 8;
  half8 v;
  #pragma unroll
  for (int j = 0; j < 8; ++j)
    v[j] = (_Float16)Whh[row * 128 + c0 + j];
  *(half8*)&Wpack[(size_t)i * 8] = v;
}

// ---------------------------------------------------------------------------
// Barrier-free LSTM. Block = 320 threads (5 waves), 80 nodes. Wave w owns nodes
// n0+w*16..+15 and computes all 512 gate rows per step:
//   G^T[gate][node] = Whh(A, LDS frags) x h(B, regs)  via 128 MFMAs/step.
// Per cg-group: 16 ds_read_b128 pinned BEFORE the MFMAs by sched_barrier(0),
// bias init, 16 MFMAs, fused-rcp update, h write to wave-private scratch.
__global__ __attribute__((amdgpu_flat_work_group_size(320, 320),
                          amdgpu_waves_per_eu(1, 2)))
void lstm_stream_kernel(
    const float* __restrict__ xfeat, const _Float16* __restrict__ Wpack,
    const float* __restrict__ Wih, const float* __restrict__ bih,
    const float* __restrict__ bhh, float* __restrict__ x1)
{
  extern __shared__ char dynlds[];
  _Float16* Wl  = (_Float16*)dynlds;                    // [128 tiles][64 lanes][8]
  float2*   bw  = (float2*)(dynlds + LDS_W);            // [512] (bias, wih)
  _Float16* scr = (_Float16*)(dynlds + LDS_W + LDS_BW); // [5][2048]

  const int tid  = threadIdx.x;   // 0..319
  const int w    = tid >> 6;      // wave 0..4
  const int ln   = tid & 63;
  const int nl   = ln & 15;       // node within wave
  const int quad = ln >> 4;
  const int n0   = blockIdx.x * NBB + w * NBW;

  // stage packed Whh -> LDS (coalesced float4)
  {
    const float4* src = (const float4*)Wpack;
    float4* dst = (float4*)Wl;
    for (int i = tid; i < LDS_W / 16; i += 320) dst[i] = src[i];
  }
  for (int i = tid; i < 512; i += 320)
    bw[i] = make_float2(bih[i] + bhh[i], Wih[i]);
  {
    float4* z = (float4*)scr;
    for (int i = tid; i < LDS_SCR / 16; i += 320)
      z[i] = make_float4(0.f, 0.f, 0.f, 0.f);
  }
  __syncthreads();   // the ONLY block barrier

  _Float16* myscr = scr + w * 2048;
  const float* xrow = xfeat + (size_t)(n0 + nl) * T_STEPS;

  float cst[8][4];
  #pragma unroll
  for (int cg = 0; cg < 8; ++cg)
    #pragma unroll
    for (int r = 0; r < 4; ++r) cst[cg][r] = 0.f;

  const int wq_hi = quad >> 1;
  const int j0    = (quad & 1) * 4;

  #pragma unroll 1
  for (int t = 0; t < T_STEPS; ++t) {
    // h of previous step as B-fragments (wave-private scratch, seq addresses)
    half8 Bf[4];
    #pragma unroll
    for (int kt = 0; kt < 4; ++kt)
      Bf[kt] = *(const half8*)&myscr[kt * 512 + ln * 8];
    const float xv = xrow[t];

    #pragma unroll 1
    for (int cg = 0; cg < 8; ++cg) {
      // phase 1: issue ALL 16 A-fragment loads (static indices)
      half8 Afr[16];
      #pragma unroll
      for (int kt = 0; kt < 4; ++kt)
        #pragma unroll
        for (int g = 0; g < 4; ++g)
          Afr[kt * 4 + g] =
              *(const half8*)&Wl[(size_t)(((g * 8 + cg) * 4 + kt) * 64 + ln) * 8];
      // hard fence: scheduler may NOT sink the loads past this point
      __builtin_amdgcn_sched_barrier(0);
      // phase 2: init gates (bias + x*Wih) while loads drain
      floatx4 acc[4];
      #pragma unroll
      for (int g = 0; g < 4; ++g) {
        const int base = g * 128 + cg * 16 + quad * 4;
        const float4 p0 = *(const float4*)&bw[base];
        const float4 p1 = *(const float4*)&bw[base + 2];
        acc[g][0] = p0.x + xv * p0.y;
        acc[g][1] = p0.z + xv * p0.w;
        acc[g][2] = p1.x + xv * p1.y;
        acc[g][3] = p1.z + xv * p1.w;
      }
      // phase 3: 16 MFMAs on the batch (fine-grained lgkmcnt from compiler)
      #pragma unroll
      for (int kt = 0; kt < 4; ++kt)
        #pragma unroll
        for (int g = 0; g < 4; ++g)
          acc[g] = __builtin_amdgcn_mfma_f32_16x16x32_f16(
              Afr[kt * 4 + g], Bf[kt], acc[g], 0, 0, 0);
      // phase 4: fused-rcp cell update (5 exp + 2 rcp per cell)
      half4v hpack;
      #pragma unroll
      for (int r = 0; r < 4; ++r) {
        float gi = fminf(fmaxf(acc[0][r], -20.f), 20.f);
        float gf = fminf(fmaxf(acc[1][r], -20.f), 20.f);
        float gg = fminf(fmaxf(acc[2][r], -10.f), 10.f);
        float go = fminf(fmaxf(acc[3][r], -20.f), 20.f);
        float Ae = __expf(-gf);
        float Be = __expf(-gi);
        float De = __expf(2.f * gg);
        float Ee = __expf(-go);
        float Dp = De + 1.f, Ap = Ae + 1.f, Bp = Be + 1.f;
        float Nn = cst[cg][r] * Bp * Dp + Ap * (De - 1.f);
        float cv = Nn * __builtin_amdgcn_rcpf(Ap * Bp * Dp);
        cst[cg][r] = cv;
        float cvc = fminf(fmaxf(cv, -10.f), 10.f);
        float Fe = __expf(2.f * cvc);
        hpack[r] = (_Float16)((Fe - 1.f) *
                   __builtin_amdgcn_rcpf((Ee + 1.f) * (Fe + 1.f)));
      }
      // write h into B-fragment position for the next step
      const int lp = nl + 16 * (2 * (cg & 1) + wq_hi);
      *(half4v*)&myscr[(cg >> 1) * 512 + lp * 8 + j0] = hpack;
    }
  }

  // epilogue: final h sits in scratch in B-frag order -> x1 = relu(h)
  #pragma unroll
  for (int kt = 0; kt < 4; ++kt) {
    const half8 hf = *(const half8*)&myscr[kt * 512 + ln * 8];
    float* dst = x1 + (size_t)(n0 + nl) * HDIM + kt * 32 + quad * 8;
    float4 o0, o1;
    o0.x = fmaxf((float)hf[0], 0.f); o0.y = fmaxf((float)hf[1], 0.f);
    o0.z = fmaxf((float)hf[2], 0.f); o0.w = fmaxf((float)hf[3], 0.f);
    o1.x = fmaxf((float)hf[4], 0.f); o1.y = fmaxf((float)hf[5], 0.f);
    o1.z = fmaxf((float)hf[6], 0.f); o1.w = fmaxf((float)hf[7], 0.f);
    *(float4*)dst = o0;
    *(float4*)(dst + 4) = o1;
  }
}

// ---------------------------------------------------------------------------
// Y[n][j] = sum_k X[n][k] * W[j][k].  32 nodes/block, W LDS-tiled in 64-row chunks.
template <int J>
__global__ __launch_bounds__(256) void gemm_xw(
    const float* __restrict__ X, const float* __restrict__ W, float* __restrict__ Y)
{
  __shared__ float Xs[32 * 132];
  __shared__ float Ws[64 * 132];
  const int tid = threadIdx.x;
  const int n0  = blockIdx.x * 32;
  for (int i = tid; i < 32 * 128; i += 256) {
    int nn = i >> 7, k = i & 127;
    Xs[nn * 132 + k] = X[(n0 + nn) * 128 + k];
  }
  const int nl = tid >> 3;
  const int jb = tid & 7;
  for (int c0 = 0; c0 < J; c0 += 64) {
    __syncthreads();
    for (int i = tid; i < 64 * 128; i += 256) {
      int r = i >> 7, k = i & 127;
      Ws[r * 132 + k] = W[(c0 + r) * 128 + k];
    }
    __syncthreads();
    float acc[8];
    #pragma unroll
    for (int m = 0; m < 8; ++m) acc[m] = 0.f;
    for (int k0 = 0; k0 < 128; k0 += 8) {
      float xr[8];
      #pragma unroll
      for (int r = 0; r < 8; ++r) xr[r] = Xs[nl * 132 + k0 + r];
      #pragma unroll
      for (int m = 0; m < 8; ++m) {
        const float* w = &Ws[(jb + (m << 3)) * 132 + k0];
        float a = acc[m];
        #pragma unroll
        for (int r = 0; r < 8; ++r) a += xr[r] * w[r];
        acc[m] = a;
      }
    }
    #pragma unroll
    for (int m = 0; m < 8; ++m)
      Y[(n0 + nl) * J + c0 + jb + (m << 3)] = acc[m];
  }
}

// ---------------------------------------------------------------------------
__global__ void zero_kernel(float* __restrict__ deg, int* __restrict__ cnt,
                            float* __restrict__ accum)
{
  int i = blockIdx.x * 256 + threadIdx.x;
  if (i < N_NODES) { deg[i] = 0.f; cnt[i] = 0; }
  if (i < JOUT) accum[i] = 0.f;
}

__global__ void count_kernel(const int* __restrict__ ei, const float* __restrict__ ew,
                             int* __restrict__ cnt, float* __restrict__ deg)
{
  int e = blockIdx.x * 256 + threadIdx.x;
  int c = ei[N_EDGES + e];
  atomicAdd(&cnt[c], 1);
  atomicAdd(&deg[c], ew[e]);
}

// shuffle-based exclusive scan: thread t owns elements [t*20, t*20+20).
__global__ __launch_bounds__(1024) void scan_kernel(
    const int* __restrict__ cnt, int* __restrict__ rowptr, int* __restrict__ cursor,
    const float* __restrict__ deg, float* __restrict__ dinv)
{
  const int tid  = threadIdx.x;
  const int lane = tid & 63;
  const int wv   = tid >> 6;        // 16 waves
  const int base = tid * 20;
  int vals[20];
  int sum = 0;
  if (tid < 1000) {
    #pragma unroll
    for (int j = 0; j < 20; ++j) { vals[j] = sum; sum += cnt[base + j]; }
  }
  int inc = sum;
  #pragma unroll
  for (int off = 1; off < 64; off <<= 1) {
    int t = __shfl_up(inc, off);
    if (lane >= off) inc += t;
  }
  __shared__ int wtot[16];
  __shared__ int wpre[16];
  if (lane == 63) wtot[wv] = inc;
  __syncthreads();
  if (tid == 0) {
    int s = 0;
    for (int i = 0; i < 16; ++i) { wpre[i] = s; s += wtot[i]; }
    rowptr[N_NODES] = s;
  }
  __syncthreads();
  if (tid < 1000) {
    int off = wpre[wv] + (inc - sum);
    #pragma unroll
    for (int j = 0; j < 20; ++j) {
      int v = off + vals[j];
      rowptr[base + j] = v;
      cursor[base + j] = v;
    }
  }
  for (int i = tid; i < N_NODES; i += 1024)
    dinv[i] = rsqrtf(deg[i] + 1.0f);   // +1 = self-loop weight
}

__global__ void fill_kernel(const int* __restrict__ ei, const float* __restrict__ ew,
                            const float* __restrict__ dinv, int* __restrict__ cursor,
                            int* __restrict__ esrc, float* __restrict__ ewn)
{
  int e = blockIdx.x * 256 + threadIdx.x;
  int r = ei[e];
  int c = ei[N_EDGES + e];
  int p = atomicAdd(&cursor[c], 1);
  esrc[p] = r;
  ewn[p]  = ew[e] * dinv[r];   // pre-scale by dinv[row]
}

// ---------------------------------------------------------------------------
// GCN aggregation: one wave per destination node; 64-edge tiles staged in LDS,
// broadcast loop unrolled x4. x2 = relu(agg + b).
__global__ __launch_bounds__(256) void gcn_agg_kernel(
    const float* __restrict__ y, const float* __restrict__ dinv,
    const int* __restrict__ rowptr, const int* __restrict__ esrc,
    const float* __restrict__ ewn, const float* __restrict__ gcn_b,
    float* __restrict__ x2)
{
  __shared__ float2 stg[4][64];
  const int lane = threadIdx.x & 63;
  const int wv = threadIdx.x >> 6;
  const int c = blockIdx.x * 4 + wv;
  const float dc = dinv[c];
  const float2* y2 = (const float2*)y;
  float2 yc = y2[c * 64 + lane];
  float ax = yc.x * dc * dc, ay = yc.y * dc * dc;   // self-loop term
  const int e0 = rowptr[c], e1 = rowptr[c + 1];
  for (int tb = e0; tb < e1; tb += 64) {
    const int cnt = min(64, e1 - tb);
    const int k = tb + lane;
    if (k < e1) stg[wv][lane] = make_float2(__int_as_float(esrc[k]), ewn[k] * dc);
    __builtin_amdgcn_wave_barrier();
    int i = 0;
    for (; i + 4 <= cnt; i += 4) {
      float2 p0 = stg[wv][i],     p1 = stg[wv][i + 1];
      float2 p2 = stg[wv][i + 2], p3 = stg[wv][i + 3];
      const float2 a0 = y2[(size_t)__float_as_int(p0.x) * 64 + lane];
      const float2 a1 = y2[(size_t)__float_as_int(p1.x) * 64 + lane];
      const float2 a2 = y2[(size_t)__float_as_int(p2.x) * 64 + lane];
      const float2 a3 = y2[(size_t)__float_as_int(p3.x) * 64 + lane];
      ax += a0.x * p0.y + a1.x * p1.y + a2.x * p2.y + a3.x * p3.y;
      ay += a0.y * p0.y + a1.y * p1.y + a2.y * p2.y + a3.y * p3.y;
    }
    for (; i < cnt; ++i) {
      float2 p0 = stg[wv][i];
      const float2 a0 = y2[(size_t)__float_as_int(p0.x) * 64 + lane];
      ax += a0.x * p0.y; ay += a0.y * p0.y;
    }
    __builtin_amdgcn_wave_barrier();
  }
  int j0 = lane * 2;
  x2[c * 128 + j0]     = fmaxf(ax + gcn_b[j0], 0.f);
  x2[c * 128 + j0 + 1] = fmaxf(ay + gcn_b[j0 + 1], 0.f);
}

// ---------------------------------------------------------------------------
// Per-node attention logits: a_src/a_dst [N][4] (padded float4)
__global__ __launch_bounds__(256) void gat_att_kernel(
    const float* __restrict__ xh, const float* __restrict__ att_src,
    const float* __restrict__ att_dst, float4* __restrict__ asrc,
    float4* __restrict__ adst)
{
  const int lane = threadIdx.x & 63;
  const int nd = blockIdx.x * 4 + (threadIdx.x >> 6);
  float s[3], d[3];
  #pragma unroll
  for (int h = 0; h < 3; ++h) {
    float xv = xh[nd * JOUT + h * 64 + lane];
    s[h] = xv * att_src[h * 64 + lane];
    d[h] = xv * att_dst[h * 64 + lane];
  }
  #pragma unroll
  for (int off = 1; off < 64; off <<= 1) {
    #pragma unroll
    for (int h = 0; h < 3; ++h) {
      s[h] += __shfl_xor(s[h], off);
      d[h] += __shfl_xor(d[h], off);
    }
  }
  if (lane == 0) {
    asrc[nd] = make_float4(s[0], s[1], s[2], 0.f);
    adst[nd] = make_float4(d[0], d[1], d[2], 0.f);
  }
}

// GAT: softmax over incoming edges (incl self-loop) + weighted agg.
// One wave per node; first-tile alpha cached in regs; 64-edge LDS-staged tiles.
__global__ __launch_bounds__(256) void gat_agg_kernel(
    const float* __restrict__ xh, const float4* __restrict__ asrc,
    const float4* __restrict__ adst, const int* __restrict__ rowptr,
    const int* __restrict__ esrc, float* __restrict__ accum)
{
  __shared__ float4 cstg[4][64];
  const int lane = threadIdx.x & 63;
  const int wv = threadIdx.x >> 6;
  const int c = blockIdx.x * 4 + wv;
  const int e0 = rowptr[c], e1 = rowptr[c + 1];
  float4 adc = adst[c];
  float4 asc = asrc[c];
  float self0 = lrelu(asc.x + adc.x);
  float self1 = lrelu(asc.y + adc.y);
  float self2 = lrelu(asc.z + adc.z);

  const bool has = (e0 + lane < e1);
  int s_first = 0;
  float v0 = -3.0e38f, v1 = -3.0e38f, v2 = -3.0e38f;
  if (has) {
    s_first = esrc[e0 + lane];
    float4 av = asrc[s_first];
    v0 = lrelu(av.x + adc.x);
    v1 = lrelu(av.y + adc.y);
    v2 = lrelu(av.z + adc.z);
  }
  float m0 = fmaxf(self0, v0), m1 = fmaxf(self1, v1), m2 = fmaxf(self2, v2);
  for (int k = e0 + 64 + lane; k < e1; k += 64) {
    float4 av = asrc[esrc[k]];
    m0 = fmaxf(m0, lrelu(av.x + adc.x));
    m1 = fmaxf(m1, lrelu(av.y + adc.y));
    m2 = fmaxf(m2, lrelu(av.z + adc.z));
  }
  #pragma unroll
  for (int off = 1; off < 64; off <<= 1) {
    m0 = fmaxf(m0, __shfl_xor(m0, off));
    m1 = fmaxf(m1, __shfl_xor(m1, off));
    m2 = fmaxf(m2, __shfl_xor(m2, off));
  }
  float ex0 = has ? __expf(v0 - m0) : 0.f;
  float ex1 = has ? __expf(v1 - m1) : 0.f;
  float ex2 = has ? __expf(v2 - m2) : 0.f;
  float d0 = ex0, d1 = ex1, d2 = ex2;
  for (int k = e0 + 64 + lane; k < e1; k += 64) {
    float4 av = asrc[esrc[k]];
    d0 += __expf(lrelu(av.x + adc.x) - m0);
    d1 += __expf(lrelu(av.y + adc.y) - m1);
    d2 += __expf(lrelu(av.z + adc.z) - m2);
  }
  #pragma unroll
  for (int off = 1; off < 64; off <<= 1) {
    d0 += __shfl_xor(d0, off);
    d1 += __shfl_xor(d1, off);
    d2 += __shfl_xor(d2, off);
  }
  float se0 = __expf(self0 - m0), se1 = __expf(self1 - m1), se2 = __expf(self2 - m2);
  d0 += se0; d1 += se1; d2 += se2;
  float iv0 = 1.f / d0, iv1 = 1.f / d1, iv2 = 1.f / d2;

  float o0 = se0 * iv0 * xh[c * JOUT + lane];
  float o1 = se1 * iv1 * xh[c * JOUT + 64 + lane];
  float o2 = se2 * iv2 * xh[c * JOUT + 128 + lane];

  for (int tb = e0; tb < e1; tb += 64) {
    const int cnt = min(64, e1 - tb);
    if (tb == e0) {
      if (has)
        cstg[wv][lane] = make_float4(__int_as_float(s_first),
                                     ex0 * iv0, ex1 * iv1, ex2 * iv2);
    } else {
      const int k = tb + lane;
      if (k < e1) {
        int s = esrc[k];
        float4 av = asrc[s];
        cstg[wv][lane] = make_float4(__int_as_float(s),
            __expf(lrelu(av.x + adc.x) - m0) * iv0,
            __expf(lrelu(av.y + adc.y) - m1) * iv1,
            __expf(lrelu(av.z + adc.z) - m2) * iv2);
      }
    }
    __builtin_amdgcn_wave_barrier();
    int i = 0;
    for (; i + 2 <= cnt; i += 2) {
      float4 q0 = cstg[wv][i], q1 = cstg[wv][i + 1];
      const float* r0 = xh + (size_t)__float_as_int(q0.x) * JOUT;
      const float* r1 = xh + (size_t)__float_as_int(q1.x) * JOUT;
      float a0 = r0[lane], b0 = r0[64 + lane], g0 = r0[128 + lane];
      float a1 = r1[lane], b1 = r1[64 + lane], g1 = r1[128 + lane];
      o0 += q0.y * a0 + q1.y * a1;
      o1 += q0.z * b0 + q1.z * b1;
      o2 += q0.w * g0 + q1.w * g1;
    }
    for (; i < cnt; ++i) {
      float4 q0 = cstg[wv][i];
      const float* r0 = xh + (size_t)__float_as_int(q0.x) * JOUT;
      o0 += q0.y * r0[lane];
      o1 += q0.z * r0[64 + lane];
      o2 += q0.w * r0[128 + lane];
    }
    __builtin_amdgcn_wave_barrier();
  }

  __shared__ float red[4][JOUT];
  red[wv][lane]       = o0;
  red[wv][64 + lane]  = o1;
  red[wv][128 + lane] = o2;
  __syncthreads();
  if (threadIdx.x < JOUT) {
    float sum = red[0][threadIdx.x] + red[1][threadIdx.x] +
                red[2][threadIdx.x] + red[3][threadIdx.x];
    atomicAdd(&accum[threadIdx.x], sum);
  }
}

__global__ void finalize_kernel(const float* __restrict__ accum,
                                const float* __restrict__ gat_b,
                                float* __restrict__ out)
{
  int j = threadIdx.x;
  if (j < JOUT) out[j] = accum[j] * (1.0f / N_NODES) + gat_b[j];
}

// ---------------------------------------------------------------------------
extern "C" void kernel_launch(void* const* d_in, const int* in_sizes, int n_in,
                              void* d_out, int out_size, void* d_ws, size_t ws_size,
                              hipStream_t stream)
{
  const float* xfeat = (const float*)d_in[0];
  const int*   eidx  = (const int*)d_in[1];
  const float* eattr = (const float*)d_in[2];
  const float* Wih   = (const float*)d_in[3];
  const float* Whh   = (const float*)d_in[4];
  const float* bihp  = (const float*)d_in[5];
  const float* bhhp  = (const float*)d_in[6];
  const float* gcnW  = (const float*)d_in[7];
  const float* gcnb  = (const float*)d_in[8];
  const float* gatW  = (const float*)d_in[9];
  const float* attS  = (const float*)d_in[10];
  const float* attD  = (const float*)d_in[11];
  const float* gatb  = (const float*)d_in[12];
  float* out = (float*)d_out;

  char* ws = (char*)d_ws;
  size_t off = 0;
  auto alloc = [&](size_t bytes) {
    char* p = ws + off;
    off += (bytes + 255) & ~size_t(255);
    return p;
  };
  float*     x1     = (float*)alloc((size_t)N_NODES * 128 * 4);
  float*     y      = (float*)alloc((size_t)N_NODES * 128 * 4);
  float*     x2     = (float*)alloc((size_t)N_NODES * 128 * 4);
  float*     xh     = (float*)alloc((size_t)N_NODES * 192 * 4);
  float4*    asrc   = (float4*)alloc((size_t)N_NODES * 16);
  float4*    adst   = (float4*)alloc((size_t)N_NODES * 16);
  float*     deg    = (float*)alloc((size_t)N_NODES * 4);
  float*     dinv   = (float*)alloc((size_t)N_NODES * 4);
  int*       cnt    = (int*)alloc((size_t)N_NODES * 4);
  int*       rowptr = (int*)alloc((size_t)(N_NODES + 1) * 4);
  int*       cursor = (int*)alloc((size_t)N_NODES * 4);
  int*       esrc   = (int*)alloc((size_t)N_EDGES * 4);
  float*     ewn    = (float*)alloc((size_t)N_EDGES * 4);
  float*     accum  = (float*)alloc(JOUT * 4);
  _Float16*  wpack  = (_Float16*)alloc(131072);

  // opt-in to >64KB dynamic LDS for the barrier-free LSTM (idempotent)
  hipFuncSetAttribute((const void*)lstm_stream_kernel,
                      hipFuncAttributeMaxDynamicSharedMemorySize, LDS_TOTAL);

  zero_kernel<<<(N_NODES + 255) / 256, 256, 0, stream>>>(deg, cnt, accum);
  pack_whh_kernel<<<32, 256, 0, stream>>>(Whh, wpack);
  lstm_stream_kernel<<<N_NODES / NBB, 320, LDS_TOTAL, stream>>>(
      xfeat, wpack, Wih, bihp, bhhp, x1);
  count_kernel<<<N_EDGES / 256, 256, 0, stream>>>(eidx, eattr, cnt, deg);
  scan_kernel<<<1, 1024, 0, stream>>>(cnt, rowptr, cursor, deg, dinv);
  fill_kernel<<<N_EDGES / 256, 256, 0, stream>>>(eidx, eattr, dinv, cursor, esrc, ewn);
  gemm_xw<128><<<N_NODES / 32, 256, 0, stream>>>(x1, gcnW, y);
  gcn_agg_kernel<<<N_NODES / 4, 256, 0, stream>>>(y, dinv, rowptr, esrc, ewn, gcnb, x2);
  gemm_xw<192><<<N_NODES / 32, 256, 0, stream>>>(x2, gatW, xh);
  gat_att_kernel<<<N_NODES / 4, 256, 0, stream>>>(xh, attS, attD, asrc, adst);
  gat_agg_kernel<<<N_NODES / 4, 256, 0, stream>>>(xh, asrc, adst, rowptr, esrc, accum);
  finalize_kernel<<<1, 256, 0, stream>>>(accum, gatb, out);
}